// Round 9
// baseline (464.122 us; speedup 1.0000x reference)
//
#include <hip/hip_runtime.h>
#include <stdint.h>

// LSTM autoencoder B=32768 T=30 I=4 H=64 L=32, fp32 in/out.
// v21 = v20.1 (32x32 3-role clusters, 230us) + invariant-work cuts using the
// measured VGPR slack (84 used / 168 cap at 3 waves/SIMD):
//  1. dec1 latent-term precompute: Wih3*latent + b3 is CONSTANT across all
//     30 dec steps -> latA[4] (f32x16, 64 VGPR) computed once; per-step
//     dec1 = 4 MFMA32/gate (was 6 + bias reads). -8 MFMA32, -24 LDS
//     reads per wave-step. Bit-identical accumulation order.
//  2. enc2 bias hoist b2r[4] (role 2, enc phase; shares regs with latA
//     across phases): -16 LDS reads/step.
//  3. Single barrier per step via double-buffered h1/h2 images (+24KB LDS,
//     still 1 block/CU): barriers per phase 60 -> 30.
// __launch_bounds__(768,3) pins allocator <=168 VGPR (v19 lesson).
// Rationale: v20.1 counters show VALU-busy time invariant ~141us (61.3% x
// 230); dur above it = 18% idle + LDS/MFMA exposure. These cuts shrink
// both the exposed work and the sync overhead.
// Structure: 32-batch clusters of 3 waves (w0/w1 = enc1/dec1 unit-halves,
// w2 = enc2+dec2), 12 waves/block, 128 batch/block, grid 256, 1 block/CU,
// 3 waves/SIMD (each SIMD hosts one wave of each role).
// Math/quantization identical: 2-term x + 2-term bias in fold k-slots,
// log2e folded into weights, unitH = 5 exp2 + 2 rcp, 1-term bf16 h.
// absmax 9.77e-4.
// Layouts: C/D 32x32: col=lane&31, row=(reg&3)+8*(reg>>2)+4*(lane>>5)
// [m74/m101 HW-verified]; A/B: m|n=lane&31, k=(lane>>5)*8+j (generalized
// from verified 16x16 m120). dec2 keeps 16x16 (gates=16).

typedef unsigned short u16;
typedef unsigned int u32;
typedef __attribute__((ext_vector_type(8))) short bf16x8;
typedef __attribute__((ext_vector_type(4))) float f32x4;
typedef __attribute__((ext_vector_type(16))) float f32x16;
typedef __attribute__((ext_vector_type(4))) u32 u32x4;
typedef __attribute__((ext_vector_type(2))) u32 u32x2;

#define BATCH 32768
#define TT 30
#define IN 4
#define WAVES 12
#define BLOCKT (WAVES * 64)   // 768
#define MBC 32                // batches per cluster (3 waves)
#define NCL 4                 // clusters per block
#define BPB (NCL * MBC)       // 128 -> grid 256, 1 block/CU

#define LOG2E 1.4426950408889634f
#define LOG2E2 2.8853900817779268f

// ---- LDS word offsets ----
// enc weights
#define O_WHH1 0        // 8192
#define O_FOLD 8192     // 2048
#define O_WIH2 10240    // 4096
#define O_WHH2 14336    // 2048 -> 16384
// dec weights (restaged into same region)
#define O_WHH3 0        // 8192
#define O_WIH3 8192     // 4096 -> 12288
#define O_WIH4 12288    // 512 -> 12800
#define O_W4HHF 12800   // 64 -> 12864
// biases (persist across restage)
#define O_B2F 16384     // 128
#define O_B3F 16512     // 256
#define O_B4F 16768     // 16
#define O_BUFS 16784
// per-cluster: h1/h3 DBUF 2048w (2 x 1024) | h2 DBUF 1024w (2 x 512,
// gbuf aliases in dec) | h4 128w
#define PBUF 3200
#define SMEM_WORDS (O_BUFS + NCL * PBUF)   // 29584
#define SMEM_BYTES (SMEM_WORDS * 4)        // 118336 <= 163840

#define WB() __builtin_amdgcn_wave_barrier()
// arg order: A = weight frag, B = data frag.
#define MFMA32(a, b, c) __builtin_amdgcn_mfma_f32_32x32x16_bf16((a), (b), (c), 0, 0, 0)
#define MFMA16(a, b, c) __builtin_amdgcn_mfma_f32_16x16x32_bf16((a), (b), (c), 0, 0, 0)

__device__ __forceinline__ u16 f2bf(float f) {   // RNE fp32->bf16 (staging)
    u32 u = __float_as_uint(f);
    u += 0x7fffu + ((u >> 16) & 1u);
    return (u16)(u >> 16);
}
__device__ __forceinline__ float bf2f(u16 v) { return __uint_as_float(((u32)v) << 16); }

__device__ __forceinline__ u32 cvtpk2(float a, float b) {   // packed RNE fp32x2->bf16x2
    u32 d;
    asm("v_cvt_pk_bf16_f32 %0, %1, %2" : "=v"(d) : "v"(a), "v"(b));
    return d;
}

// Fused LSTM cell update. Inputs pre-scaled (i,f,o by log2e; g by 2*log2e).
__device__ __forceinline__ float unitH(float yi, float yf, float yg, float yo, float& c) {
    const float ei = __builtin_amdgcn_exp2f(-yi);
    const float ef = __builtin_amdgcn_exp2f(-yf);
    const float eg = __builtin_amdgcn_exp2f(yg);
    const float eo = __builtin_amdgcn_exp2f(-yo);
    const float Z = (1.f + ei) * (1.f + eg);
    const float X = 1.f + ef;
    const float num = fmaf(eg - 1.f, X, c * Z);
    c = num * __builtin_amdgcn_rcpf(X * Z);
    const float ec = __builtin_amdgcn_exp2f(c * LOG2E2);
    return (ec - 1.f) * __builtin_amdgcn_rcpf((1.f + eo) * (1.f + ec));
}

// Stage fp32 W[N][K] -> bf16, 32x32x16 frag order, gate-scaled.
template <int KT16, int GS>
__device__ __forceinline__ void stage32(u16* dst, const float* src, int N, int tid) {
    const int K = KT16 * 16;
    const int total = N * K;
    for (int idx = tid; idx < total; idx += BLOCKT) {
        const int j = idx & 7;
        const int l = (idx >> 3) & 63;
        const int pr = idx >> 9;
        const int kt = pr % KT16;
        const int nt = pr / KT16;
        const int n = nt * 32 + (l & 31);
        const int k = kt * 16 + ((l >> 5) << 3) + j;
        const float s = (((n >> GS) & 3) == 2) ? LOG2E2 : LOG2E;
        dst[idx] = f2bf(src[n * K + k] * s);
    }
}

// Stage fp32 W[N][K] -> bf16, 16x16x32 frag order (dec2's W4ih), gate-scaled.
template <int KT, int GS>
__device__ __forceinline__ void stage16(u16* dst, const float* src, int N, int tid) {
    const int K = KT * 32;
    const int total = N * K;
    for (int idx = tid; idx < total; idx += BLOCKT) {
        const int j = idx & 7;
        const int l = (idx >> 3) & 63;
        const int pr = idx >> 9;
        const int kt = pr & (KT - 1);
        const int nt = pr / KT;
        const int n = (nt << 4) | (l & 15);
        const int k = (kt << 5) + ((l >> 4) << 3) + j;
        const float s = (((n >> GS) & 3) == 2) ? LOG2E2 : LOG2E;
        dst[idx] = f2bf(src[n * K + k] * s);
    }
}

// load a staged fragment: P = u16 base, IDX = fragment index
#define LD8(P, IDX) (*reinterpret_cast<const bf16x8*>((P) + ((IDX) * 64 + lane) * 8))

// init f32x16 acc from fp32 bias array at row base RB (rows RB..RB+31)
#define BINIT(DST, BP, RB)                                                               \
    _Pragma("unroll") for (int p_ = 0; p_ < 4; ++p_) {                                   \
        const f32x4 b_ = *reinterpret_cast<const f32x4*>((BP) + (RB) + p_ * 8 + 4 * hi); \
        (DST)[4 * p_ + 0] = b_[0]; (DST)[4 * p_ + 1] = b_[1];                            \
        (DST)[4 * p_ + 2] = b_[2]; (DST)[4 * p_ + 3] = b_[3];                            \
    }

// 16 unitH + packed h write. Writer cell r=4p+q: unit u = BKT*16+8p+4hi+q,
// batch c31. B-frag slot: kt=BKT+(p>>1), half=(p&1), j=4hi+q -> b64/p.
#define CELL16(AI, AF, AG, AO, CST, IMG, BKT)                                                        \
    _Pragma("unroll") for (int p_ = 0; p_ < 4; ++p_) {                                               \
        const float h0_ = unitH((AI)[4*p_+0], (AF)[4*p_+0], (AG)[4*p_+0], (AO)[4*p_+0], (CST)[4*p_+0]); \
        const float h1_ = unitH((AI)[4*p_+1], (AF)[4*p_+1], (AG)[4*p_+1], (AO)[4*p_+1], (CST)[4*p_+1]); \
        const float h2_ = unitH((AI)[4*p_+2], (AF)[4*p_+2], (AG)[4*p_+2], (AO)[4*p_+2], (CST)[4*p_+2]); \
        const float h3_ = unitH((AI)[4*p_+3], (AF)[4*p_+3], (AG)[4*p_+3], (AO)[4*p_+3], (CST)[4*p_+3]); \
        u32x2 wv_;                                                                                   \
        wv_.x = cvtpk2(h0_, h1_);                                                                    \
        wv_.y = cvtpk2(h2_, h3_);                                                                    \
        *reinterpret_cast<u32x2*>((IMG) + (((BKT) + (p_ >> 1)) * 64 + (p_ & 1) * 32 + c31) * 8 + 4 * hi) = wv_; \
    }

// enc1 gate-tile G (rows = gate G, units role*32..+31): fold + 4x Whh1
#define E1G(DST, G) {                                                  \
        f32x16 a_ = MFMA32(foldr[G], xB, z16);                         \
        a_ = MFMA32(LD8(Whh1p, (2 * (G) + role) * 4 + 0), h1B0, a_);   \
        a_ = MFMA32(LD8(Whh1p, (2 * (G) + role) * 4 + 1), h1B1, a_);   \
        a_ = MFMA32(LD8(Whh1p, (2 * (G) + role) * 4 + 2), h1B2, a_);   \
        a_ = MFMA32(LD8(Whh1p, (2 * (G) + role) * 4 + 3), h1B3, a_);   \
        DST = a_; }

// enc2 gate-tile G (rows = gate G, units 0..31), bias from hoisted b2r
#define E2G(DST, G) {                                                  \
        f32x16 a_ = b2r[G];                                            \
        a_ = MFMA32(LD8(Wih2p, (G) * 4 + 0), h1B0, a_);                \
        a_ = MFMA32(LD8(Wih2p, (G) * 4 + 1), h1B1, a_);                \
        a_ = MFMA32(LD8(Wih2p, (G) * 4 + 2), h1B2, a_);                \
        a_ = MFMA32(LD8(Wih2p, (G) * 4 + 3), h1B3, a_);                \
        a_ = MFMA32(LD8(Whh2p, (G) * 2 + 0), h2B0, a_);                \
        a_ = MFMA32(LD8(Whh2p, (G) * 2 + 1), h2B1, a_);                \
        DST = a_; }

// dec1 gate-tile G: precomputed latA (bias + Wih3*latent) + 4x Whh3
#define D1G(DST, G) {                                                  \
        f32x16 a_ = latA[G];                                           \
        a_ = MFMA32(LD8(Whh3p, (2 * (G) + role) * 4 + 0), h3B0, a_);   \
        a_ = MFMA32(LD8(Whh3p, (2 * (G) + role) * 4 + 1), h3B1, a_);   \
        a_ = MFMA32(LD8(Whh3p, (2 * (G) + role) * 4 + 2), h3B2, a_);   \
        a_ = MFMA32(LD8(Whh3p, (2 * (G) + role) * 4 + 3), h3B3, a_);   \
        DST = a_; }

// dec2 B-frag address in the h3 image (16x16 consumer of 32-format image)
#define D2ADDR(M, BH) ((((2 * (M) + (quad >> 1)) * 64) + (quad & 1) * 32 + (BH) * 16 + col16) * 8)

// dec2 body for timestep T (role 2): 2 batch-halves, reads h3r/bufH4
#define DEC2BODY(T, H3R) {                                                              \
        const bf16x8 dB00 = *reinterpret_cast<const bf16x8*>((H3R) + D2ADDR(0, 0));     \
        const bf16x8 dB10 = *reinterpret_cast<const bf16x8*>((H3R) + D2ADDR(1, 0));     \
        const bf16x8 dB01 = *reinterpret_cast<const bf16x8*>((H3R) + D2ADDR(0, 1));     \
        const bf16x8 dB11 = *reinterpret_cast<const bf16x8*>((H3R) + D2ADDR(1, 1));     \
        const float4 hv0 = *reinterpret_cast<const float4*>(bufH4 + col16 * 4);         \
        const float4 hv1 = *reinterpret_cast<const float4*>(bufH4 + (16 + col16) * 4);  \
        f32x4 a0 = b4v, a1 = b4v;                                                       \
        _Pragma("unroll") for (int r_ = 0; r_ < 4; ++r_) {                              \
            float s0 = a0[r_], s1 = a1[r_];                                             \
            s0 = fmaf(w4r[r_].x, hv0.x, s0); s0 = fmaf(w4r[r_].y, hv0.y, s0);           \
            s0 = fmaf(w4r[r_].z, hv0.z, s0); s0 = fmaf(w4r[r_].w, hv0.w, s0);           \
            s1 = fmaf(w4r[r_].x, hv1.x, s1); s1 = fmaf(w4r[r_].y, hv1.y, s1);           \
            s1 = fmaf(w4r[r_].z, hv1.z, s1); s1 = fmaf(w4r[r_].w, hv1.w, s1);           \
            a0[r_] = s0; a1[r_] = s1;                                                   \
        }                                                                               \
        a0 = MFMA16(w4a0, dB00, a0); a0 = MFMA16(w4a1, dB10, a0);                       \
        a1 = MFMA16(w4a0, dB01, a1); a1 = MFMA16(w4a1, dB11, a1);                       \
        WB();                                                                           \
        *reinterpret_cast<f32x4*>(gbuf + col16 * 16 + quad * 4) = a0;                   \
        *reinterpret_cast<f32x4*>(gbuf + (16 + col16) * 16 + quad * 4) = a1;            \
        WB();                                                                           \
        {                                                                               \
            const int u4_ = lane & 3, mb_ = lane >> 2;                                  \
            const float h0_ = unitH(gbuf[mb_ * 16 + u4_], gbuf[mb_ * 16 + 4 + u4_],     \
                                    gbuf[mb_ * 16 + 8 + u4_], gbuf[mb_ * 16 + 12 + u4_], c4a); \
            out[((size_t)(b0w + mb_) * TT + (T)) * IN + u4_] = h0_;                     \
            bufH4[mb_ * 4 + u4_] = h0_;                                                 \
            const int b1_ = 16 + mb_;                                                   \
            const float h1_ = unitH(gbuf[b1_ * 16 + u4_], gbuf[b1_ * 16 + 4 + u4_],     \
                                    gbuf[b1_ * 16 + 8 + u4_], gbuf[b1_ * 16 + 12 + u4_], c4b); \
            out[((size_t)(b0w + b1_) * TT + (T)) * IN + u4_] = h1_;                     \
            bufH4[b1_ * 4 + u4_] = h1_;                                                 \
        }                                                                               \
        WB(); }

__global__ __launch_bounds__(BLOCKT, 3)
void lstm_ae(
    const float* __restrict__ x,
    const float* __restrict__ w1ih, const float* __restrict__ w1hh,
    const float* __restrict__ b1i, const float* __restrict__ b1h,
    const float* __restrict__ w2ih, const float* __restrict__ w2hh,
    const float* __restrict__ b2i, const float* __restrict__ b2h,
    const float* __restrict__ w3ih, const float* __restrict__ w3hh,
    const float* __restrict__ b3i, const float* __restrict__ b3h,
    const float* __restrict__ w4ih, const float* __restrict__ w4hh,
    const float* __restrict__ b4i, const float* __restrict__ b4h,
    float* __restrict__ out) {
    extern __shared__ float smem[];
    float* W = smem;

    const int tid = threadIdx.x;
    const int wave = tid >> 6, lane = tid & 63;
    const int cl = wave / 3, role = wave % 3;   // 4 clusters x {enc1-ub0, enc1-ub1, enc2}
    const int c31 = lane & 31, hi = lane >> 5;
    const int col16 = lane & 15, quad = lane >> 4;

    float* pb = smem + O_BUFS + cl * PBUF;
    u16* h1d = (u16*)pb;              // 4096 u16: h1/h3 dbuf, buf p at p<<11
    u16* h2d = (u16*)(pb + 2048);     // 2048 u16: h2 dbuf, buf p at p<<10
    float* gbuf = pb + 2048;          // 512 f: dec2 transpose (aliases h2 dbuf)
    float* bufH4 = pb + 3072;         // 128 f: dec2 h feedback

    const int b0w = blockIdx.x * BPB + cl * MBC;

    // ---------------- stage ENCODER weights + biases ----------------
    stage32<4, 6>((u16*)(W + O_WHH1), w1hh, 256, tid);
    stage32<4, 5>((u16*)(W + O_WIH2), w2ih, 128, tid);
    stage32<2, 5>((u16*)(W + O_WHH2), w2hh, 128, tid);
    {   // fold A-frags: lo lanes [whi x4 | whi x4]; hi lanes [wlo x4 | bhi blo 0 0]
        u16* F = (u16*)(W + O_FOLD);
        for (int idx = tid; idx < 4096; idx += BLOCKT) {
            const int j = idx & 7;
            const int l = (idx >> 3) & 63;
            const int nt = idx >> 9;
            const int m = nt * 32 + (l & 31);
            const int hif = l >> 5;
            const float sc = ((m >> 6) == 2) ? LOG2E2 : LOG2E;
            u16 v = 0;
            if (!hif) {
                v = f2bf(w1ih[m * 4 + (j & 3)] * sc);
            } else if (j < 4) {
                const float w = w1ih[m * 4 + j] * sc;
                v = f2bf(w - bf2f(f2bf(w)));
            } else if (j == 4) {
                v = f2bf((b1i[m] + b1h[m]) * sc);
            } else if (j == 5) {
                const float b = (b1i[m] + b1h[m]) * sc;
                v = f2bf(b - bf2f(f2bf(b)));
            }
            F[idx] = v;
        }
    }
    float* b2f = W + O_B2F;
    float* b3f = W + O_B3F;
    float* b4f = W + O_B4F;
    for (int i = tid; i < 128; i += BLOCKT)
        b2f[i] = (b2i[i] + b2h[i]) * (((i >> 5) == 2) ? LOG2E2 : LOG2E);
    for (int i = tid; i < 256; i += BLOCKT)
        b3f[i] = (b3i[i] + b3h[i]) * (((i >> 6) == 2) ? LOG2E2 : LOG2E);
    for (int i = tid; i < 16; i += BLOCKT)
        b4f[i] = (b4i[i] + b4h[i]) * (((i >> 2) == 2) ? LOG2E2 : LOG2E);
    if (role == 2) {   // zero h2 buf0 (h1 needs no zero: prologue writes full image)
        u32* z = (u32*)pb;
        for (int i = lane; i < 512; i += 64) z[2048 + i] = 0u;
    }
    __syncthreads();

    const u16* Whh1p = (const u16*)(W + O_WHH1);
    const u16* Wih2p = (const u16*)(W + O_WIH2);
    const u16* Whh2p = (const u16*)(W + O_WHH2);
    const u16* FOLDp = (const u16*)(W + O_FOLD);

    const f32x16 z16 = {0.f, 0.f, 0.f, 0.f, 0.f, 0.f, 0.f, 0.f,
                        0.f, 0.f, 0.f, 0.f, 0.f, 0.f, 0.f, 0.f};
    // cst: role<2 -> c1; role==2 -> c2. Re-zeroed for dec (role<2 -> c3).
    float cst[16];
#pragma unroll
    for (int r = 0; r < 16; ++r) cst[r] = 0.f;

    bf16x8 foldr[4] = {};
    f32x16 b2r[4];   // role2 enc bias hoist (filled below)
    if (role < 2) {
#pragma unroll
        for (int g = 0; g < 4; ++g) foldr[g] = LD8(FOLDp, 2 * g + role);
    } else {
#pragma unroll
        for (int g = 0; g < 4; ++g) { BINIT(b2r[g], b2f, g * 32) }
    }

    float4 xcur = {0.f, 0.f, 0.f, 0.f};
    if (role < 2)
        xcur = *reinterpret_cast<const float4*>(x + ((size_t)(b0w + c31) * TT + 0) * IN);

    // x B-frag: lo lanes [xhi x4 | xlo x4]; hi lanes [xhi x4 | 1.0 1.0 0 0]
    auto buildX = [&](const float4 xc) -> bf16x8 {
        const u32 h01 = cvtpk2(xc.x, xc.y);
        const u32 h23 = cvtpk2(xc.z, xc.w);
        const float r0 = xc.x - __uint_as_float(h01 << 16);
        const float r1 = xc.y - __uint_as_float(h01 & 0xffff0000u);
        const float r2 = xc.z - __uint_as_float(h23 << 16);
        const float r3 = xc.w - __uint_as_float(h23 & 0xffff0000u);
        const u32 l01 = cvtpk2(r0, r1);
        const u32 l23 = cvtpk2(r2, r3);
        u32x4 v;
        v.x = h01;
        v.y = h23;
        v.z = hi ? 0x3F803F80u : l01;
        v.w = hi ? 0u : l23;
        return __builtin_bit_cast(bf16x8, v);
    };

    // ================= encoder (1 barrier/step, dbuf h) =================
    if (role < 2) {   // prologue: enc1[0], h1[-1]=0 -> h1 buf0
        const bf16x8 xB = buildX(xcur);
        xcur = *reinterpret_cast<const float4*>(x + ((size_t)(b0w + c31) * TT + 1) * IN);
        f32x16 aI = MFMA32(foldr[0], xB, z16);
        f32x16 aF = MFMA32(foldr[1], xB, z16);
        f32x16 aG = MFMA32(foldr[2], xB, z16);
        f32x16 aO = MFMA32(foldr[3], xB, z16);
        CELL16(aI, aF, aG, aO, cst, h1d, 2 * role)
    }
    __syncthreads();

    for (int t = 0; t < TT - 1; ++t) {
        const u16* h1r = h1d + ((t & 1) << 11);          // h1[t]
        u16* h1w = h1d + (((t + 1) & 1) << 11);          // h1[t+1]
        const u16* h2r = h2d + ((t & 1) << 10);          // h2[t-1]
        u16* h2w = h2d + (((t + 1) & 1) << 10);          // h2[t]
        if (role == 2) {   // enc2[t]
            const bf16x8 h1B0 = *reinterpret_cast<const bf16x8*>(h1r + (0 * 64 + lane) * 8);
            const bf16x8 h1B1 = *reinterpret_cast<const bf16x8*>(h1r + (1 * 64 + lane) * 8);
            const bf16x8 h1B2 = *reinterpret_cast<const bf16x8*>(h1r + (2 * 64 + lane) * 8);
            const bf16x8 h1B3 = *reinterpret_cast<const bf16x8*>(h1r + (3 * 64 + lane) * 8);
            const bf16x8 h2B0 = *reinterpret_cast<const bf16x8*>(h2r + (0 * 64 + lane) * 8);
            const bf16x8 h2B1 = *reinterpret_cast<const bf16x8*>(h2r + (1 * 64 + lane) * 8);
            f32x16 aI, aF, aG, aO;
            E2G(aI, 0) E2G(aF, 1) E2G(aG, 2) E2G(aO, 3)
            CELL16(aI, aF, aG, aO, cst, h2w, 0)
        } else {           // enc1[t+1]
            const bf16x8 h1B0 = *reinterpret_cast<const bf16x8*>(h1r + (0 * 64 + lane) * 8);
            const bf16x8 h1B1 = *reinterpret_cast<const bf16x8*>(h1r + (1 * 64 + lane) * 8);
            const bf16x8 h1B2 = *reinterpret_cast<const bf16x8*>(h1r + (2 * 64 + lane) * 8);
            const bf16x8 h1B3 = *reinterpret_cast<const bf16x8*>(h1r + (3 * 64 + lane) * 8);
            const bf16x8 xB = buildX(xcur);
            const int tn = (t + 2 < TT) ? t + 2 : TT - 1;
            xcur = *reinterpret_cast<const float4*>(x + ((size_t)(b0w + c31) * TT + tn) * IN);
            f32x16 aI, aF, aG, aO;
            E1G(aI, 0) E1G(aF, 1) E1G(aG, 2) E1G(aO, 3)
            CELL16(aI, aF, aG, aO, cst, h1w, 2 * role)
        }
        __syncthreads();
    }
    if (role == 2) {   // epilogue: enc2[TT-1] -> latent into h2 buf0
        const u16* h1r = h1d + (((TT - 1) & 1) << 11);
        const u16* h2r = h2d + (((TT - 1) & 1) << 10);
        u16* h2w = h2d;   // buf0
        const bf16x8 h1B0 = *reinterpret_cast<const bf16x8*>(h1r + (0 * 64 + lane) * 8);
        const bf16x8 h1B1 = *reinterpret_cast<const bf16x8*>(h1r + (1 * 64 + lane) * 8);
        const bf16x8 h1B2 = *reinterpret_cast<const bf16x8*>(h1r + (2 * 64 + lane) * 8);
        const bf16x8 h1B3 = *reinterpret_cast<const bf16x8*>(h1r + (3 * 64 + lane) * 8);
        const bf16x8 h2B0 = *reinterpret_cast<const bf16x8*>(h2r + (0 * 64 + lane) * 8);
        const bf16x8 h2B1 = *reinterpret_cast<const bf16x8*>(h2r + (1 * 64 + lane) * 8);
        f32x16 aI, aF, aG, aO;
        E2G(aI, 0) E2G(aF, 1) E2G(aG, 2) E2G(aO, 3)
        CELL16(aI, aF, aG, aO, cst, h2w, 0)
    }
    __syncthreads();   // latent visible in h2 buf0

    // ---------------- re-stage DECODER weights + hoists ----------------
    stage32<4, 6>((u16*)(W + O_WHH3), w3hh, 256, tid);
    stage32<2, 6>((u16*)(W + O_WIH3), w3ih, 256, tid);
    stage16<2, 2>((u16*)(W + O_WIH4), w4ih, 16, tid);
    for (int i = tid; i < 64; i += BLOCKT)
        W[O_W4HHF + i] = w4hh[i] * ((((i >> 4) & 3) == 2) ? LOG2E2 : LOG2E);

    float c4a = 0.f, c4b = 0.f;
    bf16x8 latB0 = {}, latB1 = {};
    if (role < 2) {   // latent hoist from h2 buf0 (untouched by restage)
        latB0 = *reinterpret_cast<const bf16x8*>(h2d + (0 * 64 + lane) * 8);
        latB1 = *reinterpret_cast<const bf16x8*>(h2d + (1 * 64 + lane) * 8);
    } else {
        for (int i = lane; i < 128; i += 64) bufH4[i] = 0.f;
    }
#pragma unroll
    for (int r = 0; r < 16; ++r) cst[r] = 0.f;   // re-zero: dec c3 (role<2)
    __syncthreads();   // dec weights visible

    const u16* Whh3p = (const u16*)(W + O_WHH3);
    const u16* Wih3p = (const u16*)(W + O_WIH3);
    const u16* Wih4p = (const u16*)(W + O_WIH4);
    const float* W4hhF = W + O_W4HHF;
    bf16x8 w4a0 = {}, w4a1 = {};
    f32x4 b4v = {0.f, 0.f, 0.f, 0.f};
    float4 w4r[4] = {};
    f32x16 latA[4];   // role<2: bias + Wih3*latent, constant across t
    if (role < 2) {
#pragma unroll
        for (int g = 0; g < 4; ++g) {
            f32x16 a;
            BINIT(a, b3f, (2 * g + role) * 32)
            a = MFMA32(LD8(Wih3p, (2 * g + role) * 2 + 0), latB0, a);
            a = MFMA32(LD8(Wih3p, (2 * g + role) * 2 + 1), latB1, a);
            latA[g] = a;
        }
    } else {   // dec2 hoists (tiny)
        w4a0 = LD8(Wih4p, 0);
        w4a1 = LD8(Wih4p, 1);
        b4v = *reinterpret_cast<const f32x4*>(b4f + quad * 4);
#pragma unroll
        for (int r = 0; r < 4; ++r)
            w4r[r] = *reinterpret_cast<const float4*>(W4hhF + (quad * 4 + r) * 4);
    }

    // ================= decoder (1 barrier/step, dbuf h3) =================
    if (role < 2) {   // prologue: dec1[0], h3[-1]=0 -> h3 buf0
        CELL16(latA[0], latA[1], latA[2], latA[3], cst, h1d, 2 * role)
    }
    __syncthreads();

    for (int t = 0; t < TT - 1; ++t) {
        const u16* h3r = h1d + ((t & 1) << 11);          // h3[t]
        u16* h3w = h1d + (((t + 1) & 1) << 11);          // h3[t+1]
        if (role == 2) {   // dec2[t]
            DEC2BODY(t, h3r)
        } else {           // dec1[t+1]
            const bf16x8 h3B0 = *reinterpret_cast<const bf16x8*>(h3r + (0 * 64 + lane) * 8);
            const bf16x8 h3B1 = *reinterpret_cast<const bf16x8*>(h3r + (1 * 64 + lane) * 8);
            const bf16x8 h3B2 = *reinterpret_cast<const bf16x8*>(h3r + (2 * 64 + lane) * 8);
            const bf16x8 h3B3 = *reinterpret_cast<const bf16x8*>(h3r + (3 * 64 + lane) * 8);
            f32x16 aI, aF, aG, aO;
            D1G(aI, 0) D1G(aF, 1) D1G(aG, 2) D1G(aO, 3)
            CELL16(aI, aF, aG, aO, cst, h3w, 2 * role)
        }
        __syncthreads();
    }
    if (role == 2) {   // epilogue: dec2[TT-1]
        const u16* h3r = h1d + (((TT - 1) & 1) << 11);
        DEC2BODY(TT - 1, h3r)
    }
}

extern "C" void kernel_launch(void* const* d_in, const int* in_sizes, int n_in,
                              void* d_out, int out_size, void* d_ws, size_t ws_size,
                              hipStream_t stream) {
    (void)in_sizes; (void)n_in; (void)d_ws; (void)ws_size; (void)out_size;
    hipFuncSetAttribute(reinterpret_cast<const void*>(lstm_ae),
                        hipFuncAttributeMaxDynamicSharedMemorySize, SMEM_BYTES);
    const float* xi = (const float*)d_in[0];
    const float* w1ih = (const float*)d_in[1];
    const float* w1hh = (const float*)d_in[2];
    const float* b1i = (const float*)d_in[3];
    const float* b1h = (const float*)d_in[4];
    const float* w2ih = (const float*)d_in[5];
    const float* w2hh = (const float*)d_in[6];
    const float* b2i = (const float*)d_in[7];
    const float* b2h = (const float*)d_in[8];
    const float* w3ih = (const float*)d_in[9];
    const float* w3hh = (const float*)d_in[10];
    const float* b3i = (const float*)d_in[11];
    const float* b3h = (const float*)d_in[12];
    const float* w4ih = (const float*)d_in[13];
    const float* w4hh = (const float*)d_in[14];
    const float* b4i = (const float*)d_in[15];
    const float* b4h = (const float*)d_in[16];
    float* out = (float*)d_out;

    lstm_ae<<<dim3(BATCH / BPB), dim3(BLOCKT), SMEM_BYTES, stream>>>(
        xi, w1ih, w1hh, b1i, b1h, w2ih, w2hh, b2i, b2h,
        w3ih, w3hh, b3i, b3h, w4ih, w4hh, b4i, b4h, out);
}

// Round 10
// 284.342 us; speedup vs baseline: 1.6323x; 1.6323x over previous
//
#include <hip/hip_runtime.h>
#include <stdint.h>

// LSTM autoencoder B=32768 T=30 I=4 H=64 L=32, fp32 in/out.
// v22 = v20.1 (32x32 3-role clusters, 230us, 84 VGPR no-spill) + the
// ZERO-VGPR piece of v21: double-buffered h images, ONE __syncthreads per
// step (was 2). Barriers/phase 60 -> 30. +24KB LDS, still 1 block/CU.
// v21 post-mortem: the f32x16 hoists (b2r/latA) spilled NOT because of
// dynamic indexing but STATIC LIVENESS ACROSS ROLE BRANCHES - role<2 and
// role==2 variables are simultaneously live in the static CFG, so a
// per-role 64-VGPR hoist costs 64 in every role -> ~190 static > 168 cap
// -> allocator kept VGPR=84 and sent the arrays to scratch (FETCH 337MB).
// v22 adds NO live registers.
// Structure: 32-batch clusters of 3 waves (w0/w1 = enc1/dec1 unit-halves,
// w2 = enc2+dec2), 12 waves/block, 128 batch/block, grid 256, 1 block/CU,
// 3 waves/SIMD (each SIMD hosts one wave of each role; role imbalance is
// absorbed by SIMD sharing).
// Math/quantization identical: 2-term x + 2-term bias in fold k-slots,
// log2e folded into weights, unitH = 5 exp2 + 2 rcp, 1-term bf16 h.
// absmax 9.77e-4.
// Layouts: C/D 32x32: col=lane&31, row=(reg&3)+8*(reg>>2)+4*(lane>>5)
// [m74/m101 HW-verified]; A/B: m|n=lane&31, k=(lane>>5)*8+j (generalized
// from verified 16x16 m120). dec2 keeps 16x16 (gates=16).

typedef unsigned short u16;
typedef unsigned int u32;
typedef __attribute__((ext_vector_type(8))) short bf16x8;
typedef __attribute__((ext_vector_type(4))) float f32x4;
typedef __attribute__((ext_vector_type(16))) float f32x16;
typedef __attribute__((ext_vector_type(4))) u32 u32x4;
typedef __attribute__((ext_vector_type(2))) u32 u32x2;

#define BATCH 32768
#define TT 30
#define IN 4
#define WAVES 12
#define BLOCKT (WAVES * 64)   // 768
#define MBC 32                // batches per cluster (3 waves)
#define NCL 4                 // clusters per block
#define BPB (NCL * MBC)       // 128 -> grid 256, 1 block/CU

#define LOG2E 1.4426950408889634f
#define LOG2E2 2.8853900817779268f

// ---- LDS word offsets ----
// enc weights
#define O_WHH1 0        // 8192
#define O_FOLD 8192     // 2048
#define O_WIH2 10240    // 4096
#define O_WHH2 14336    // 2048 -> 16384
// dec weights (restaged into same region)
#define O_WHH3 0        // 8192
#define O_WIH3 8192     // 4096 -> 12288
#define O_WIH4 12288    // 512 -> 12800
#define O_W4HHF 12800   // 64 -> 12864
// biases (persist across restage)
#define O_B2F 16384     // 128
#define O_B3F 16512     // 256
#define O_B4F 16768     // 16
#define O_BUFS 16784
// per-cluster: h1/h3 DBUF 2048w (2 x 1024) | h2 DBUF 1024w (2 x 512,
// gbuf aliases buf0 in dec) | h4 128w
#define PBUF 3200
#define SMEM_WORDS (O_BUFS + NCL * PBUF)   // 29584
#define SMEM_BYTES (SMEM_WORDS * 4)        // 118336 <= 163840

#define WB() __builtin_amdgcn_wave_barrier()
// arg order: A = weight frag, B = data frag.
#define MFMA32(a, b, c) __builtin_amdgcn_mfma_f32_32x32x16_bf16((a), (b), (c), 0, 0, 0)
#define MFMA16(a, b, c) __builtin_amdgcn_mfma_f32_16x16x32_bf16((a), (b), (c), 0, 0, 0)

__device__ __forceinline__ u16 f2bf(float f) {   // RNE fp32->bf16 (staging)
    u32 u = __float_as_uint(f);
    u += 0x7fffu + ((u >> 16) & 1u);
    return (u16)(u >> 16);
}
__device__ __forceinline__ float bf2f(u16 v) { return __uint_as_float(((u32)v) << 16); }

__device__ __forceinline__ u32 cvtpk2(float a, float b) {   // packed RNE fp32x2->bf16x2
    u32 d;
    asm("v_cvt_pk_bf16_f32 %0, %1, %2" : "=v"(d) : "v"(a), "v"(b));
    return d;
}

// Fused LSTM cell update. Inputs pre-scaled (i,f,o by log2e; g by 2*log2e).
__device__ __forceinline__ float unitH(float yi, float yf, float yg, float yo, float& c) {
    const float ei = __builtin_amdgcn_exp2f(-yi);
    const float ef = __builtin_amdgcn_exp2f(-yf);
    const float eg = __builtin_amdgcn_exp2f(yg);
    const float eo = __builtin_amdgcn_exp2f(-yo);
    const float Z = (1.f + ei) * (1.f + eg);
    const float X = 1.f + ef;
    const float num = fmaf(eg - 1.f, X, c * Z);
    c = num * __builtin_amdgcn_rcpf(X * Z);
    const float ec = __builtin_amdgcn_exp2f(c * LOG2E2);
    return (ec - 1.f) * __builtin_amdgcn_rcpf((1.f + eo) * (1.f + ec));
}

// Stage fp32 W[N][K] -> bf16, 32x32x16 frag order, gate-scaled.
template <int KT16, int GS>
__device__ __forceinline__ void stage32(u16* dst, const float* src, int N, int tid) {
    const int K = KT16 * 16;
    const int total = N * K;
    for (int idx = tid; idx < total; idx += BLOCKT) {
        const int j = idx & 7;
        const int l = (idx >> 3) & 63;
        const int pr = idx >> 9;
        const int kt = pr % KT16;
        const int nt = pr / KT16;
        const int n = nt * 32 + (l & 31);
        const int k = kt * 16 + ((l >> 5) << 3) + j;
        const float s = (((n >> GS) & 3) == 2) ? LOG2E2 : LOG2E;
        dst[idx] = f2bf(src[n * K + k] * s);
    }
}

// Stage fp32 W[N][K] -> bf16, 16x16x32 frag order (dec2's W4ih), gate-scaled.
template <int KT, int GS>
__device__ __forceinline__ void stage16(u16* dst, const float* src, int N, int tid) {
    const int K = KT * 32;
    const int total = N * K;
    for (int idx = tid; idx < total; idx += BLOCKT) {
        const int j = idx & 7;
        const int l = (idx >> 3) & 63;
        const int pr = idx >> 9;
        const int kt = pr & (KT - 1);
        const int nt = pr / KT;
        const int n = (nt << 4) | (l & 15);
        const int k = (kt << 5) + ((l >> 4) << 3) + j;
        const float s = (((n >> GS) & 3) == 2) ? LOG2E2 : LOG2E;
        dst[idx] = f2bf(src[n * K + k] * s);
    }
}

// load a staged fragment: P = u16 base, IDX = fragment index
#define LD8(P, IDX) (*reinterpret_cast<const bf16x8*>((P) + ((IDX) * 64 + lane) * 8))

// init f32x16 acc from fp32 bias array at row base RB (rows RB..RB+31)
#define BINIT(DST, BP, RB)                                                               \
    _Pragma("unroll") for (int p_ = 0; p_ < 4; ++p_) {                                   \
        const f32x4 b_ = *reinterpret_cast<const f32x4*>((BP) + (RB) + p_ * 8 + 4 * hi); \
        (DST)[4 * p_ + 0] = b_[0]; (DST)[4 * p_ + 1] = b_[1];                            \
        (DST)[4 * p_ + 2] = b_[2]; (DST)[4 * p_ + 3] = b_[3];                            \
    }

// 16 unitH + packed h write. Writer cell r=4p+q: unit u = BKT*16+8p+4hi+q,
// batch c31. B-frag slot: kt=BKT+(p>>1), half=(p&1), j=4hi+q -> b64/p.
#define CELL16(AI, AF, AG, AO, CST, IMG, BKT)                                                        \
    _Pragma("unroll") for (int p_ = 0; p_ < 4; ++p_) {                                               \
        const float h0_ = unitH((AI)[4*p_+0], (AF)[4*p_+0], (AG)[4*p_+0], (AO)[4*p_+0], (CST)[4*p_+0]); \
        const float h1_ = unitH((AI)[4*p_+1], (AF)[4*p_+1], (AG)[4*p_+1], (AO)[4*p_+1], (CST)[4*p_+1]); \
        const float h2_ = unitH((AI)[4*p_+2], (AF)[4*p_+2], (AG)[4*p_+2], (AO)[4*p_+2], (CST)[4*p_+2]); \
        const float h3_ = unitH((AI)[4*p_+3], (AF)[4*p_+3], (AG)[4*p_+3], (AO)[4*p_+3], (CST)[4*p_+3]); \
        u32x2 wv_;                                                                                   \
        wv_.x = cvtpk2(h0_, h1_);                                                                    \
        wv_.y = cvtpk2(h2_, h3_);                                                                    \
        *reinterpret_cast<u32x2*>((IMG) + (((BKT) + (p_ >> 1)) * 64 + (p_ & 1) * 32 + c31) * 8 + 4 * hi) = wv_; \
    }

// enc1 gate-tile G (rows = gate G, units role*32..+31): fold + 4x Whh1
#define E1G(DST, G) {                                                  \
        f32x16 a_ = MFMA32(foldr[G], xB, z16);                         \
        a_ = MFMA32(LD8(Whh1p, (2 * (G) + role) * 4 + 0), h1B0, a_);   \
        a_ = MFMA32(LD8(Whh1p, (2 * (G) + role) * 4 + 1), h1B1, a_);   \
        a_ = MFMA32(LD8(Whh1p, (2 * (G) + role) * 4 + 2), h1B2, a_);   \
        a_ = MFMA32(LD8(Whh1p, (2 * (G) + role) * 4 + 3), h1B3, a_);   \
        DST = a_; }

// enc2 gate-tile G (rows = gate G, units 0..31)
#define E2G(DST, G) {                                                  \
        f32x16 a_; BINIT(a_, b2f, (G) * 32)                            \
        a_ = MFMA32(LD8(Wih2p, (G) * 4 + 0), h1B0, a_);                \
        a_ = MFMA32(LD8(Wih2p, (G) * 4 + 1), h1B1, a_);                \
        a_ = MFMA32(LD8(Wih2p, (G) * 4 + 2), h1B2, a_);                \
        a_ = MFMA32(LD8(Wih2p, (G) * 4 + 3), h1B3, a_);                \
        a_ = MFMA32(LD8(Whh2p, (G) * 2 + 0), h2B0, a_);                \
        a_ = MFMA32(LD8(Whh2p, (G) * 2 + 1), h2B1, a_);                \
        DST = a_; }

// dec1 gate-tile G: bias + 2x Wih3(latent) + 4x Whh3
#define D1G(DST, G) {                                                  \
        f32x16 a_; BINIT(a_, b3f, (2 * (G) + role) * 32)               \
        a_ = MFMA32(LD8(Wih3p, (2 * (G) + role) * 2 + 0), latB0, a_);  \
        a_ = MFMA32(LD8(Wih3p, (2 * (G) + role) * 2 + 1), latB1, a_);  \
        a_ = MFMA32(LD8(Whh3p, (2 * (G) + role) * 4 + 0), h3B0, a_);   \
        a_ = MFMA32(LD8(Whh3p, (2 * (G) + role) * 4 + 1), h3B1, a_);   \
        a_ = MFMA32(LD8(Whh3p, (2 * (G) + role) * 4 + 2), h3B2, a_);   \
        a_ = MFMA32(LD8(Whh3p, (2 * (G) + role) * 4 + 3), h3B3, a_);   \
        DST = a_; }
// dec1 prologue (h3[-1]=0): skip Whh3
#define D1G0(DST, G) {                                                 \
        f32x16 a_; BINIT(a_, b3f, (2 * (G) + role) * 32)               \
        a_ = MFMA32(LD8(Wih3p, (2 * (G) + role) * 2 + 0), latB0, a_);  \
        a_ = MFMA32(LD8(Wih3p, (2 * (G) + role) * 2 + 1), latB1, a_);  \
        DST = a_; }

// dec2 B-frag address in the h3 image (16x16 consumer of 32-format image)
#define D2ADDR(M, BH) ((((2 * (M) + (quad >> 1)) * 64) + (quad & 1) * 32 + (BH) * 16 + col16) * 8)

// dec2 body for timestep T (role 2): 2 batch-halves, reads H3R/bufH4
#define DEC2BODY(T, H3R) {                                                              \
        const bf16x8 dB00 = *reinterpret_cast<const bf16x8*>((H3R) + D2ADDR(0, 0));     \
        const bf16x8 dB10 = *reinterpret_cast<const bf16x8*>((H3R) + D2ADDR(1, 0));     \
        const bf16x8 dB01 = *reinterpret_cast<const bf16x8*>((H3R) + D2ADDR(0, 1));     \
        const bf16x8 dB11 = *reinterpret_cast<const bf16x8*>((H3R) + D2ADDR(1, 1));     \
        const float4 hv0 = *reinterpret_cast<const float4*>(bufH4 + col16 * 4);         \
        const float4 hv1 = *reinterpret_cast<const float4*>(bufH4 + (16 + col16) * 4);  \
        f32x4 a0 = b4v, a1 = b4v;                                                       \
        _Pragma("unroll") for (int r_ = 0; r_ < 4; ++r_) {                              \
            float s0 = a0[r_], s1 = a1[r_];                                             \
            s0 = fmaf(w4r[r_].x, hv0.x, s0); s0 = fmaf(w4r[r_].y, hv0.y, s0);           \
            s0 = fmaf(w4r[r_].z, hv0.z, s0); s0 = fmaf(w4r[r_].w, hv0.w, s0);           \
            s1 = fmaf(w4r[r_].x, hv1.x, s1); s1 = fmaf(w4r[r_].y, hv1.y, s1);           \
            s1 = fmaf(w4r[r_].z, hv1.z, s1); s1 = fmaf(w4r[r_].w, hv1.w, s1);           \
            a0[r_] = s0; a1[r_] = s1;                                                   \
        }                                                                               \
        a0 = MFMA16(w4a0, dB00, a0); a0 = MFMA16(w4a1, dB10, a0);                       \
        a1 = MFMA16(w4a0, dB01, a1); a1 = MFMA16(w4a1, dB11, a1);                       \
        WB();                                                                           \
        *reinterpret_cast<f32x4*>(gbuf + col16 * 16 + quad * 4) = a0;                   \
        *reinterpret_cast<f32x4*>(gbuf + (16 + col16) * 16 + quad * 4) = a1;            \
        WB();                                                                           \
        {                                                                               \
            const int u4_ = lane & 3, mb_ = lane >> 2;                                  \
            const float h0_ = unitH(gbuf[mb_ * 16 + u4_], gbuf[mb_ * 16 + 4 + u4_],     \
                                    gbuf[mb_ * 16 + 8 + u4_], gbuf[mb_ * 16 + 12 + u4_], c4a); \
            out[((size_t)(b0w + mb_) * TT + (T)) * IN + u4_] = h0_;                     \
            bufH4[mb_ * 4 + u4_] = h0_;                                                 \
            const int b1_ = 16 + mb_;                                                   \
            const float h1_ = unitH(gbuf[b1_ * 16 + u4_], gbuf[b1_ * 16 + 4 + u4_],     \
                                    gbuf[b1_ * 16 + 8 + u4_], gbuf[b1_ * 16 + 12 + u4_], c4b); \
            out[((size_t)(b0w + b1_) * TT + (T)) * IN + u4_] = h1_;                     \
            bufH4[b1_ * 4 + u4_] = h1_;                                                 \
        }                                                                               \
        WB(); }

__global__ __launch_bounds__(BLOCKT)
void lstm_ae(
    const float* __restrict__ x,
    const float* __restrict__ w1ih, const float* __restrict__ w1hh,
    const float* __restrict__ b1i, const float* __restrict__ b1h,
    const float* __restrict__ w2ih, const float* __restrict__ w2hh,
    const float* __restrict__ b2i, const float* __restrict__ b2h,
    const float* __restrict__ w3ih, const float* __restrict__ w3hh,
    const float* __restrict__ b3i, const float* __restrict__ b3h,
    const float* __restrict__ w4ih, const float* __restrict__ w4hh,
    const float* __restrict__ b4i, const float* __restrict__ b4h,
    float* __restrict__ out) {
    extern __shared__ float smem[];
    float* W = smem;

    const int tid = threadIdx.x;
    const int wave = tid >> 6, lane = tid & 63;
    const int cl = wave / 3, role = wave % 3;   // 4 clusters x {enc1-ub0, enc1-ub1, enc2}
    const int c31 = lane & 31, hi = lane >> 5;
    const int col16 = lane & 15, quad = lane >> 4;

    float* pb = smem + O_BUFS + cl * PBUF;
    u16* h1d = (u16*)pb;              // 4096 u16: h1/h3 dbuf, buf p at p<<11
    u16* h2d = (u16*)(pb + 2048);     // 2048 u16: h2 dbuf, buf p at p<<10
    float* gbuf = pb + 2048;          // 512 f: dec2 transpose (aliases h2 buf0)
    float* bufH4 = pb + 3072;         // 128 f: dec2 h feedback

    const int b0w = blockIdx.x * BPB + cl * MBC;

    // ---------------- stage ENCODER weights + biases ----------------
    stage32<4, 6>((u16*)(W + O_WHH1), w1hh, 256, tid);
    stage32<4, 5>((u16*)(W + O_WIH2), w2ih, 128, tid);
    stage32<2, 5>((u16*)(W + O_WHH2), w2hh, 128, tid);
    {   // fold A-frags: lo lanes [whi x4 | whi x4]; hi lanes [wlo x4 | bhi blo 0 0]
        u16* F = (u16*)(W + O_FOLD);
        for (int idx = tid; idx < 4096; idx += BLOCKT) {
            const int j = idx & 7;
            const int l = (idx >> 3) & 63;
            const int nt = idx >> 9;
            const int m = nt * 32 + (l & 31);
            const int hif = l >> 5;
            const float sc = ((m >> 6) == 2) ? LOG2E2 : LOG2E;
            u16 v = 0;
            if (!hif) {
                v = f2bf(w1ih[m * 4 + (j & 3)] * sc);
            } else if (j < 4) {
                const float w = w1ih[m * 4 + j] * sc;
                v = f2bf(w - bf2f(f2bf(w)));
            } else if (j == 4) {
                v = f2bf((b1i[m] + b1h[m]) * sc);
            } else if (j == 5) {
                const float b = (b1i[m] + b1h[m]) * sc;
                v = f2bf(b - bf2f(f2bf(b)));
            }
            F[idx] = v;
        }
    }
    float* b2f = W + O_B2F;
    float* b3f = W + O_B3F;
    float* b4f = W + O_B4F;
    for (int i = tid; i < 128; i += BLOCKT)
        b2f[i] = (b2i[i] + b2h[i]) * (((i >> 5) == 2) ? LOG2E2 : LOG2E);
    for (int i = tid; i < 256; i += BLOCKT)
        b3f[i] = (b3i[i] + b3h[i]) * (((i >> 6) == 2) ? LOG2E2 : LOG2E);
    for (int i = tid; i < 16; i += BLOCKT)
        b4f[i] = (b4i[i] + b4h[i]) * (((i >> 2) == 2) ? LOG2E2 : LOG2E);
    if (role == 2) {   // zero h2 buf0 (= h2[-1]; h1 needs no zero)
        u32* z = (u32*)pb;
        for (int i = lane; i < 512; i += 64) z[2048 + i] = 0u;
    }
    __syncthreads();

    const u16* Whh1p = (const u16*)(W + O_WHH1);
    const u16* Wih2p = (const u16*)(W + O_WIH2);
    const u16* Whh2p = (const u16*)(W + O_WHH2);
    const u16* FOLDp = (const u16*)(W + O_FOLD);

    const f32x16 z16 = {0.f, 0.f, 0.f, 0.f, 0.f, 0.f, 0.f, 0.f,
                        0.f, 0.f, 0.f, 0.f, 0.f, 0.f, 0.f, 0.f};
    // cst: role<2 -> c1; role==2 -> c2. Re-zeroed for dec (role<2 -> c3).
    float cst[16];
#pragma unroll
    for (int r = 0; r < 16; ++r) cst[r] = 0.f;

    bf16x8 foldr[4] = {};
    if (role < 2) {
#pragma unroll
        for (int g = 0; g < 4; ++g) foldr[g] = LD8(FOLDp, 2 * g + role);
    }

    float4 xcur = {0.f, 0.f, 0.f, 0.f};
    if (role < 2)
        xcur = *reinterpret_cast<const float4*>(x + ((size_t)(b0w + c31) * TT + 0) * IN);

    // x B-frag: lo lanes [xhi x4 | xlo x4]; hi lanes [xhi x4 | 1.0 1.0 0 0]
    auto buildX = [&](const float4 xc) -> bf16x8 {
        const u32 h01 = cvtpk2(xc.x, xc.y);
        const u32 h23 = cvtpk2(xc.z, xc.w);
        const float r0 = xc.x - __uint_as_float(h01 << 16);
        const float r1 = xc.y - __uint_as_float(h01 & 0xffff0000u);
        const float r2 = xc.z - __uint_as_float(h23 << 16);
        const float r3 = xc.w - __uint_as_float(h23 & 0xffff0000u);
        const u32 l01 = cvtpk2(r0, r1);
        const u32 l23 = cvtpk2(r2, r3);
        u32x4 v;
        v.x = h01;
        v.y = h23;
        v.z = hi ? 0x3F803F80u : l01;
        v.w = hi ? 0u : l23;
        return __builtin_bit_cast(bf16x8, v);
    };

    // ================= encoder (1 barrier/step, dbuf h) =================
    if (role < 2) {   // prologue: enc1[0], h1[-1]=0 -> h1 buf0
        const bf16x8 xB = buildX(xcur);
        xcur = *reinterpret_cast<const float4*>(x + ((size_t)(b0w + c31) * TT + 1) * IN);
        f32x16 aI = MFMA32(foldr[0], xB, z16);
        f32x16 aF = MFMA32(foldr[1], xB, z16);
        f32x16 aG = MFMA32(foldr[2], xB, z16);
        f32x16 aO = MFMA32(foldr[3], xB, z16);
        CELL16(aI, aF, aG, aO, cst, h1d, 2 * role)
    }
    __syncthreads();

    for (int t = 0; t < TT - 1; ++t) {
        const u16* h1r = h1d + ((t & 1) << 11);          // h1[t]
        u16* h1w = h1d + (((t + 1) & 1) << 11);          // h1[t+1]
        const u16* h2r = h2d + ((t & 1) << 10);          // h2[t-1]
        u16* h2w = h2d + (((t + 1) & 1) << 10);          // h2[t]
        if (role == 2) {   // enc2[t]
            const bf16x8 h1B0 = *reinterpret_cast<const bf16x8*>(h1r + (0 * 64 + lane) * 8);
            const bf16x8 h1B1 = *reinterpret_cast<const bf16x8*>(h1r + (1 * 64 + lane) * 8);
            const bf16x8 h1B2 = *reinterpret_cast<const bf16x8*>(h1r + (2 * 64 + lane) * 8);
            const bf16x8 h1B3 = *reinterpret_cast<const bf16x8*>(h1r + (3 * 64 + lane) * 8);
            const bf16x8 h2B0 = *reinterpret_cast<const bf16x8*>(h2r + (0 * 64 + lane) * 8);
            const bf16x8 h2B1 = *reinterpret_cast<const bf16x8*>(h2r + (1 * 64 + lane) * 8);
            f32x16 aI, aF, aG, aO;
            E2G(aI, 0) E2G(aF, 1) E2G(aG, 2) E2G(aO, 3)
            CELL16(aI, aF, aG, aO, cst, h2w, 0)
        } else {           // enc1[t+1]
            const bf16x8 h1B0 = *reinterpret_cast<const bf16x8*>(h1r + (0 * 64 + lane) * 8);
            const bf16x8 h1B1 = *reinterpret_cast<const bf16x8*>(h1r + (1 * 64 + lane) * 8);
            const bf16x8 h1B2 = *reinterpret_cast<const bf16x8*>(h1r + (2 * 64 + lane) * 8);
            const bf16x8 h1B3 = *reinterpret_cast<const bf16x8*>(h1r + (3 * 64 + lane) * 8);
            const bf16x8 xB = buildX(xcur);
            const int tn = (t + 2 < TT) ? t + 2 : TT - 1;
            xcur = *reinterpret_cast<const float4*>(x + ((size_t)(b0w + c31) * TT + tn) * IN);
            f32x16 aI, aF, aG, aO;
            E1G(aI, 0) E1G(aF, 1) E1G(aG, 2) E1G(aO, 3)
            CELL16(aI, aF, aG, aO, cst, h1w, 2 * role)
        }
        __syncthreads();
    }
    if (role == 2) {   // epilogue: enc2[TT-1] -> latent into h2 buf0
        const u16* h1r = h1d + (((TT - 1) & 1) << 11);
        const u16* h2r = h2d + (((TT - 1) & 1) << 10);
        u16* h2w = h2d;   // buf0
        const bf16x8 h1B0 = *reinterpret_cast<const bf16x8*>(h1r + (0 * 64 + lane) * 8);
        const bf16x8 h1B1 = *reinterpret_cast<const bf16x8*>(h1r + (1 * 64 + lane) * 8);
        const bf16x8 h1B2 = *reinterpret_cast<const bf16x8*>(h1r + (2 * 64 + lane) * 8);
        const bf16x8 h1B3 = *reinterpret_cast<const bf16x8*>(h1r + (3 * 64 + lane) * 8);
        const bf16x8 h2B0 = *reinterpret_cast<const bf16x8*>(h2r + (0 * 64 + lane) * 8);
        const bf16x8 h2B1 = *reinterpret_cast<const bf16x8*>(h2r + (1 * 64 + lane) * 8);
        f32x16 aI, aF, aG, aO;
        E2G(aI, 0) E2G(aF, 1) E2G(aG, 2) E2G(aO, 3)
        CELL16(aI, aF, aG, aO, cst, h2w, 0)
    }
    __syncthreads();   // latent visible in h2 buf0

    // ---------------- re-stage DECODER weights + small hoists ----------------
    stage32<4, 6>((u16*)(W + O_WHH3), w3hh, 256, tid);
    stage32<2, 6>((u16*)(W + O_WIH3), w3ih, 256, tid);
    stage16<2, 2>((u16*)(W + O_WIH4), w4ih, 16, tid);
    for (int i = tid; i < 64; i += BLOCKT)
        W[O_W4HHF + i] = w4hh[i] * ((((i >> 4) & 3) == 2) ? LOG2E2 : LOG2E);

    float c4a = 0.f, c4b = 0.f;
    bf16x8 latB0 = {}, latB1 = {};
    if (role < 2) {   // latent hoist from h2 buf0 (untouched by restage)
        latB0 = *reinterpret_cast<const bf16x8*>(h2d + (0 * 64 + lane) * 8);
        latB1 = *reinterpret_cast<const bf16x8*>(h2d + (1 * 64 + lane) * 8);
    } else {
        for (int i = lane; i < 128; i += 64) bufH4[i] = 0.f;
    }
#pragma unroll
    for (int r = 0; r < 16; ++r) cst[r] = 0.f;   // re-zero: dec c3 (role<2)
    __syncthreads();   // dec weights visible

    const u16* Whh3p = (const u16*)(W + O_WHH3);
    const u16* Wih3p = (const u16*)(W + O_WIH3);
    const u16* Wih4p = (const u16*)(W + O_WIH4);
    const float* W4hhF = W + O_W4HHF;
    bf16x8 w4a0 = {}, w4a1 = {};
    f32x4 b4v = {0.f, 0.f, 0.f, 0.f};
    float4 w4r[4] = {};
    if (role == 2) {   // dec2 hoists (tiny, ~28 VGPR)
        w4a0 = LD8(Wih4p, 0);
        w4a1 = LD8(Wih4p, 1);
        b4v = *reinterpret_cast<const f32x4*>(b4f + quad * 4);
#pragma unroll
        for (int r = 0; r < 4; ++r)
            w4r[r] = *reinterpret_cast<const float4*>(W4hhF + (quad * 4 + r) * 4);
    }

    // ================= decoder (1 barrier/step, dbuf h3) =================
    if (role < 2) {   // prologue: dec1[0], h3[-1]=0 -> h3 buf0
        f32x16 aI, aF, aG, aO;
        D1G0(aI, 0) D1G0(aF, 1) D1G0(aG, 2) D1G0(aO, 3)
        CELL16(aI, aF, aG, aO, cst, h1d, 2 * role)
    }
    __syncthreads();

    for (int t = 0; t < TT - 1; ++t) {
        const u16* h3r = h1d + ((t & 1) << 11);          // h3[t]
        u16* h3w = h1d + (((t + 1) & 1) << 11);          // h3[t+1]
        if (role == 2) {   // dec2[t]
            DEC2BODY(t, h3r)
        } else {           // dec1[t+1]
            const bf16x8 h3B0 = *reinterpret_cast<const bf16x8*>(h3r + (0 * 64 + lane) * 8);
            const bf16x8 h3B1 = *reinterpret_cast<const bf16x8*>(h3r + (1 * 64 + lane) * 8);
            const bf16x8 h3B2 = *reinterpret_cast<const bf16x8*>(h3r + (2 * 64 + lane) * 8);
            const bf16x8 h3B3 = *reinterpret_cast<const bf16x8*>(h3r + (3 * 64 + lane) * 8);
            f32x16 aI, aF, aG, aO;
            D1G(aI, 0) D1G(aF, 1) D1G(aG, 2) D1G(aO, 3)
            CELL16(aI, aF, aG, aO, cst, h3w, 2 * role)
        }
        __syncthreads();
    }
    if (role == 2) {   // epilogue: dec2[TT-1]
        const u16* h3r = h1d + (((TT - 1) & 1) << 11);
        DEC2BODY(TT - 1, h3r)
    }
}

extern "C" void kernel_launch(void* const* d_in, const int* in_sizes, int n_in,
                              void* d_out, int out_size, void* d_ws, size_t ws_size,
                              hipStream_t stream) {
    (void)in_sizes; (void)n_in; (void)d_ws; (void)ws_size; (void)out_size;
    hipFuncSetAttribute(reinterpret_cast<const void*>(lstm_ae),
                        hipFuncAttributeMaxDynamicSharedMemorySize, SMEM_BYTES);
    const float* xi = (const float*)d_in[0];
    const float* w1ih = (const float*)d_in[1];
    const float* w1hh = (const float*)d_in[2];
    const float* b1i = (const float*)d_in[3];
    const float* b1h = (const float*)d_in[4];
    const float* w2ih = (const float*)d_in[5];
    const float* w2hh = (const float*)d_in[6];
    const float* b2i = (const float*)d_in[7];
    const float* b2h = (const float*)d_in[8];
    const float* w3ih = (const float*)d_in[9];
    const float* w3hh = (const float*)d_in[10];
    const float* b3i = (const float*)d_in[11];
    const float* b3h = (const float*)d_in[12];
    const float* w4ih = (const float*)d_in[13];
    const float* w4hh = (const float*)d_in[14];
    const float* b4i = (const float*)d_in[15];
    const float* b4h = (const float*)d_in[16];
    float* out = (float*)d_out;

    lstm_ae<<<dim3(BATCH / BPB), dim3(BLOCKT), SMEM_BYTES, stream>>>(
        xi, w1ih, w1hh, b1i, b1h, w2ih, w2hh, b2i, b2h,
        w3ih, w3hh, b3i, b3h, w4ih, w4hh, b4i, b4h, out);
}